// Round 7
// baseline (684.112 us; speedup 1.0000x reference)
//
#include <hip/hip_runtime.h>

// MHSA fused pipeline v7, MI355X gfx950.
// B=2, N=2048, C=1024, H=16, dim=64.
//
// v7: attn = 4-way m-split (g in 0..3, 512 m each), n-block 64 (2 n-waves),
// m-tile 32, block 512, grid 1024 -> up to 4 blocks/CU (24-32 waves/CU vs
// v6's grid-limited 16). K/V single-buffered in LDS (~34 KB) with register
// prefetch (global->reg overlapped with compute; ds_write after barrier).
// Q prep folded into attn prologue (raw fp32 Q read once per block).
// prep drops the Q section; merge unchanged from v6.

#define H 16
#define NSEQ 2048
#define CCH 1024
#define BATCH 2
#define DSTR (H * NSEQ)  // 32768

typedef __attribute__((ext_vector_type(8))) short bf16x8;
typedef __attribute__((ext_vector_type(4))) float f32x4;
typedef __attribute__((ext_vector_type(16))) float f32x16;
typedef __attribute__((ext_vector_type(4))) unsigned int uint32x4;

__device__ __forceinline__ unsigned short f2bf(float x) {
  unsigned int u = __builtin_bit_cast(unsigned int, x);
  u += 0x7FFFu + ((u >> 16) & 1u);  // RNE
  return (unsigned short)(u >> 16);
}

__device__ __forceinline__ unsigned int pack2bf(float a, float b) {
#if __has_builtin(__builtin_amdgcn_cvt_pk_bf16_f32)
  typedef __attribute__((ext_vector_type(2))) __bf16 bf16x2_t;
  bf16x2_t r = __builtin_amdgcn_cvt_pk_bf16_f32(a, b);
  return __builtin_bit_cast(unsigned int, r);
#else
  unsigned int ua = __builtin_bit_cast(unsigned int, a);
  unsigned int ub = __builtin_bit_cast(unsigned int, b);
  ua += 0x7FFFu + ((ua >> 16) & 1u);
  ub += 0x7FFFu + ((ub >> 16) & 1u);
  return __builtin_amdgcn_perm(ub, ua, 0x07060302u);
#endif
}

__device__ __forceinline__ float fast_exp2(float x) {
#if __has_builtin(__builtin_amdgcn_exp2f)
  return __builtin_amdgcn_exp2f(x);
#else
  return exp2f(x);
#endif
}

__device__ __forceinline__ void permswap32(unsigned int& a, unsigned int& b) {
#if __has_builtin(__builtin_amdgcn_permlane32_swap)
  typedef __attribute__((ext_vector_type(2))) unsigned int uint2v;
  uint2v r = __builtin_amdgcn_permlane32_swap(a, b, false, false);
  a = r[0];
  b = r[1];
#else
  unsigned int ax = (unsigned int)__shfl_xor((int)a, 32, 64);
  unsigned int bx = (unsigned int)__shfl_xor((int)b, 32, 64);
  bool lo = (threadIdx.x & 63) < 32;
  unsigned int na = lo ? a : bx;
  unsigned int nb = lo ? ax : b;
  a = na;
  b = nb;
#endif
}

__device__ __forceinline__ void gld16(const void* g, void* l) {
  __builtin_amdgcn_global_load_lds(
      (const __attribute__((address_space(1))) unsigned int*)g,
      (__attribute__((address_space(3))) unsigned int*)l, 16, 0, 0);
}

__device__ __forceinline__ f32x16 zero16() {
  f32x16 v;
#pragma unroll
  for (int i = 0; i < 16; ++i) v[i] = 0.f;
  return v;
}

// ---------------- fused prep: W permute | V convert | K transpose ----------------
// grid: [0,1024) W-rows | [1024,5120) V float4 | [5120,6144) K 64-n tiles
__global__ __launch_bounds__(256) void prep_all(const float* __restrict__ W,
                                                const float* __restrict__ v,
                                                const float* __restrict__ k,
                                                unsigned short* __restrict__ Wp,
                                                unsigned short* __restrict__ Vb,
                                                unsigned short* __restrict__ Kt) {
  __shared__ unsigned short T[64][72];
  const int bid = blockIdx.x, tid = threadIdx.x;

  if (bid < 1024) {
    const int o = bid;
    const int cp = tid * 4;
    const int hh = cp >> 6;
    const int d0 = cp & 63;
    const float* Wr = W + (size_t)o * CCH;
    ushort4 ov;
    ov.x = f2bf(Wr[(d0 + 0) * H + hh]);
    ov.y = f2bf(Wr[(d0 + 1) * H + hh]);
    ov.z = f2bf(Wr[(d0 + 2) * H + hh]);
    ov.w = f2bf(Wr[(d0 + 3) * H + hh]);
    *(ushort4*)&Wp[(size_t)o * CCH + cp] = ov;
  } else if (bid < 5120) {
    int idx = (bid - 1024) * 256 + tid;
    float4 x = ((const float4*)v)[idx];
    ushort4 o;
    o.x = f2bf(x.x); o.y = f2bf(x.y); o.z = f2bf(x.z); o.w = f2bf(x.w);
    ((ushort4*)Vb)[idx] = o;
  } else {
    // K transpose+convert to [b][h][n][d]
    const int lbid = bid - 5120;
    const int n0 = (lbid & 31) * 64;
    const int hh = (lbid >> 5) & 15;
    const int b = lbid >> 9;
    const size_t base = (size_t)b * (CCH * NSEQ) + (size_t)hh * NSEQ;
#pragma unroll
    for (int it = 0; it < 4; ++it) {
      int i4 = it * 256 + tid;
      int d = i4 >> 4;
      int nn = (i4 & 15) << 2;
      float4 val = *(const float4*)(k + base + (size_t)d * DSTR + n0 + nn);
      T[nn + 0][d] = f2bf(val.x);
      T[nn + 1][d] = f2bf(val.y);
      T[nn + 2][d] = f2bf(val.z);
      T[nn + 3][d] = f2bf(val.w);
    }
    __syncthreads();
    const size_t obase = ((size_t)(b * H + hh) * NSEQ + n0) * 64;
#pragma unroll
    for (int it = 0; it < 2; ++it) {
      int idx = it * 256 + tid;
      int row = idx >> 3, cb = idx & 7;
      *(bf16x8*)(Kt + obase + (size_t)row * 64 + cb * 8) = *(const bf16x8*)&T[row][cb * 8];
    }
  }
}

// ---------------- attention v7 ----------------
// grid (32,16,2) = 1024 blocks, block 512 = 8 waves: g = w>>1 (m-group, 512 m),
// nw = w&1 (32 n-rows each). n-block 64. m-tile 32, 16 iters per group.
__global__ __launch_bounds__(512, 6) void attn7(const float* __restrict__ q,
                                                const unsigned short* __restrict__ Kt,
                                                const unsigned short* __restrict__ Vb,
                                                unsigned short* __restrict__ xt) {
  // LDS (shorts): K[g] @ g*2048 (4 KB each, 16 KB) | V[g] @ 8192+g*2048 (16 KB)
  // Q staging (8 KB) and epilogue Oex[64][64] f32 (16 KB) reuse the K/V area.
  __shared__ __align__(16) unsigned char sbuf[32768 + 1024];
  unsigned short* KV = (unsigned short*)sbuf;
  float* lsumLDS = (float*)(sbuf + 32768);  // [4][64]
  float* Oex = (float*)sbuf;                // [64][64]
  unsigned short* Qs = KV;                  // [64][64] swizzled, transient

  const int tid = threadIdx.x;
  const int w = tid >> 6, lane = tid & 63;
  const int lane31 = lane & 31, hl = lane >> 5;
  const int g = w >> 1, nw = w & 1;
  const int gtid = nw * 64 + lane;  // 0..127 within group
  const int n0 = blockIdx.x * 64;
  const int hh = blockIdx.y, b = blockIdx.z;

  const float* Qraw = q + (size_t)b * (CCH * NSEQ) + (size_t)hh * NSEQ;
  const unsigned short* Kg = Kt + ((size_t)(b * H + hh) * NSEQ + g * 512) * 64;
  const unsigned short* Vg = Vb + (size_t)b * (CCH * NSEQ) + (size_t)hh * NSEQ + g * 512;

  unsigned short* KL = KV + g * 2048;         // [32 m][64 d], 128 B rows
  unsigned short* VL = KV + 8192 + g * 2048;  // [64 d][32 m], 64 B rows

  // ---- prologue: stage Q (fp32 -> bf16, transposed, swizzled) ----
  const float qscl = 0.022097086912079608f * 1.4426950408889634f;  // 1/sqrt(2048)*log2e
#pragma unroll
  for (int it = 0; it < 2; ++it) {
    int i4 = it * 512 + tid;  // 1024 float4
    int d = i4 >> 4;
    int nn = (i4 & 15) << 2;
    float4 val = *(const float4*)(Qraw + (size_t)d * DSTR + n0 + nn);
    int ch = d >> 3, di = d & 7;
#pragma unroll
    for (int j = 0; j < 4; ++j) {
      float x = (j == 0) ? val.x : (j == 1) ? val.y : (j == 2) ? val.z : val.w;
      int n = nn + j;
      Qs[n * 64 + (ch ^ (n & 7)) * 8 + di] = f2bf(x * qscl);
    }
  }
  __syncthreads();

  // ---- loop-invariant Q B-fragments: B[col=n=lane31][k=d] ----
  bf16x8 bQ[4];
#pragma unroll
  for (int ks = 0; ks < 4; ++ks) {
    int row = nw * 32 + lane31;
    int phys = (ks * 2 + hl) ^ (row & 7);
    bQ[ks] = *(const bf16x8*)(Qs + (size_t)row * 64 + phys * 8);
  }

  // ---- prefetch iter 0 to regs (overlaps the barrier) ----
  const int krow = gtid >> 2, kc0 = (gtid & 3) * 2;  // K: 32 rows x 8 chunks
  const int vrow = gtid >> 1, vc0 = (gtid & 1) * 2;  // V: 64 rows x 4 chunks
  bf16x8 kp[2], vp[2];
#pragma unroll
  for (int j = 0; j < 2; ++j) {
    kp[j] = *(const bf16x8*)(Kg + (size_t)krow * 64 + (kc0 + j) * 8);
    vp[j] = *(const bf16x8*)(Vg + (size_t)vrow * DSTR + (vc0 + j) * 8);
  }
  __syncthreads();  // Q reads done; safe to overwrite with K/V

#pragma unroll
  for (int j = 0; j < 2; ++j) {
    *(bf16x8*)(KL + krow * 64 + ((kc0 + j) ^ (krow & 7)) * 8) = kp[j];
    *(bf16x8*)(VL + vrow * 32 + ((vc0 + j) ^ (vrow & 3)) * 8) = vp[j];
  }
  __syncthreads();

  f32x16 O[2];  // [dt]; col = d = dt*32+lane31, regs = n-rows
  O[0] = zero16();
  O[1] = zero16();
  float lsum = 0.f;

  for (int it = 0; it < 16; ++it) {
    // prefetch next tile into regs (global, overlaps compute)
    if (it < 15) {
      const int m0n = (it + 1) * 32;
#pragma unroll
      for (int j = 0; j < 2; ++j) {
        kp[j] = *(const bf16x8*)(Kg + (size_t)(m0n + krow) * 64 + (kc0 + j) * 8);
        vp[j] = *(const bf16x8*)(Vg + (size_t)vrow * DSTR + m0n + (vc0 + j) * 8);
      }
    }

    // ---- St[m 32][n 32] = K . Q^T ----
    f32x16 St = zero16();
#pragma unroll
    for (int ks = 0; ks < 4; ++ks) {
      int phys = (ks * 2 + hl) ^ (lane31 & 7);
      bf16x8 aK = *(const bf16x8*)(KL + lane31 * 64 + phys * 8);
      St = __builtin_amdgcn_mfma_f32_32x32x16_bf16(aK, bQ[ks], St, 0, 0, 0);
    }

    // ---- P = exp2(St), pack consecutive-m pairs ----
    unsigned int pd[8];
#pragma unroll
    for (int t = 0; t < 8; ++t) {
      float e0 = fast_exp2(St[2 * t]);
      float e1 = fast_exp2(St[2 * t + 1]);
      lsum += e0 + e1;
      pd[t] = pack2bf(e0, e1);
    }

    // ---- C-layout -> A-layout in-register ----
    unsigned int s0[4] = {pd[0], pd[1], pd[2], pd[3]};
    unsigned int s1[4] = {pd[4], pd[5], pd[6], pd[7]};
    permswap32(s0[0], s0[2]);
    permswap32(s0[1], s0[3]);
    permswap32(s1[0], s1[2]);
    permswap32(s1[1], s1[3]);

    // ---- PV: O[n][d] += P[n][m] . V[d][m] ----
#pragma unroll
    for (int ms = 0; ms < 2; ++ms) {
      bf16x8 bV[2];
#pragma unroll
      for (int dt = 0; dt < 2; ++dt) {
        int row = dt * 32 + lane31;
        int phys = (ms * 2 + hl) ^ (row & 3);
        bV[dt] = *(const bf16x8*)(VL + row * 32 + phys * 8);
      }
      const unsigned int* sp = ms ? s1 : s0;
      bf16x8 aP = __builtin_bit_cast(bf16x8, (uint32x4){sp[0], sp[1], sp[2], sp[3]});
      O[0] = __builtin_amdgcn_mfma_f32_32x32x16_bf16(aP, bV[0], O[0], 0, 0, 0);
      O[1] = __builtin_amdgcn_mfma_f32_32x32x16_bf16(aP, bV[1], O[1], 0, 0, 0);
    }

    __syncthreads();  // all LDS reads of cur tile done
    if (it < 15) {
#pragma unroll
      for (int j = 0; j < 2; ++j) {
        *(bf16x8*)(KL + krow * 64 + ((kc0 + j) ^ (krow & 7)) * 8) = kp[j];
        *(bf16x8*)(VL + vrow * 32 + ((vc0 + j) ^ (vrow & 3)) * 8) = vp[j];
      }
      __syncthreads();  // writes visible
    }
  }

  // ---- epilogue: combine 4 m-groups in LDS, normalize, store ----
  lsum += __shfl_xor(lsum, 32, 64);
  if (hl == 0) lsumLDS[g * 64 + nw * 32 + lane31] = lsum;

  if (g == 3) {
#pragma unroll
    for (int dt = 0; dt < 2; ++dt)
#pragma unroll
      for (int r = 0; r < 16; ++r) {
        int nl = nw * 32 + (r & 3) + 8 * (r >> 2) + 4 * hl;
        Oex[nl * 64 + dt * 32 + lane31] = O[dt][r];
      }
  }
  __syncthreads();
  if (g == 2) {
#pragma unroll
    for (int dt = 0; dt < 2; ++dt)
#pragma unroll
      for (int r = 0; r < 16; ++r) {
        int nl = nw * 32 + (r & 3) + 8 * (r >> 2) + 4 * hl;
        Oex[nl * 64 + dt * 32 + lane31] += O[dt][r];
      }
  }
  __syncthreads();
  if (g == 1) {
#pragma unroll
    for (int dt = 0; dt < 2; ++dt)
#pragma unroll
      for (int r = 0; r < 16; ++r) {
        int nl = nw * 32 + (r & 3) + 8 * (r >> 2) + 4 * hl;
        Oex[nl * 64 + dt * 32 + lane31] += O[dt][r];
      }
  }
  __syncthreads();
  if (g == 0) {
    const size_t xb = (size_t)b * ((size_t)NSEQ * CCH);
#pragma unroll
    for (int rq = 0; rq < 4; ++rq) {
      int nlb = nw * 32 + rq * 8 + 4 * hl;
      float4 l0 = *(const float4*)&lsumLDS[nlb];
      float4 l1 = *(const float4*)&lsumLDS[64 + nlb];
      float4 l2 = *(const float4*)&lsumLDS[128 + nlb];
      float4 l3 = *(const float4*)&lsumLDS[192 + nlb];
      float inv0 = 1.0f / (l0.x + l1.x + l2.x + l3.x);
      float inv1 = 1.0f / (l0.y + l1.y + l2.y + l3.y);
      float inv2 = 1.0f / (l0.z + l1.z + l2.z + l3.z);
      float inv3 = 1.0f / (l0.w + l1.w + l2.w + l3.w);
#pragma unroll
      for (int dt = 0; dt < 2; ++dt) {
        int d = dt * 32 + lane31;
#pragma unroll
        for (int rr = 0; rr < 4; ++rr) {
          int r = rq * 4 + rr;
          float val = O[dt][r] + Oex[(nlb + rr) * 64 + d];
          float inv = (rr == 0) ? inv0 : (rr == 1) ? inv1 : (rr == 2) ? inv2 : inv3;
          int n = n0 + nlb + rr;
          xt[xb + (size_t)n * CCH + hh * 64 + d] = f2bf(val * inv);
        }
      }
    }
  }
}

// ---------------- merge GEMM: 64x64 tiles, grid 1024, dbuf (unchanged v6) ----------------
__global__ __launch_bounds__(256) void merge5(const unsigned short* __restrict__ Wp,
                                              const unsigned short* __restrict__ xt,
                                              const float* __restrict__ bias,
                                              float* __restrict__ out) {
  __shared__ unsigned short At[2][64 * 64];
  __shared__ unsigned short Bt[2][64 * 64];
  const int tid = threadIdx.x;
  const int w = tid >> 6, lane = tid & 63;
  const int quad = lane >> 4, l16 = lane & 15;
  const int wx = w & 1, wy = w >> 1;
  const int n0 = blockIdx.x * 64, o0 = blockIdx.y * 64, b = blockIdx.z;
  const int srow = w * 8 + (lane >> 3), scb = lane & 7;
  const unsigned short* Bbase = xt + (size_t)b * ((size_t)NSEQ * CCH);

  f32x4 acc[2][2];
#pragma unroll
  for (int ot = 0; ot < 2; ++ot)
#pragma unroll
    for (int nt = 0; nt < 2; ++nt) acc[ot][nt] = (f32x4){0.f, 0.f, 0.f, 0.f};

#pragma unroll
  for (int i = 0; i < 2; ++i) {
    int row = i * 32 + srow;
    int cbl = scb ^ (row & 7);
    gld16(Wp + (size_t)(o0 + row) * CCH + cbl * 8, &At[0][(i * 32 + w * 8) * 64]);
    gld16(Bbase + (size_t)(n0 + row) * CCH + cbl * 8, &Bt[0][(i * 32 + w * 8) * 64]);
  }
  __syncthreads();

  for (int it = 0; it < 16; ++it) {
    const int cur = it & 1;
    if (it < 15) {
      const int nxt = cur ^ 1;
      const int c0 = (it + 1) * 64;
#pragma unroll
      for (int i = 0; i < 2; ++i) {
        int row = i * 32 + srow;
        int cbl = scb ^ (row & 7);
        gld16(Wp + (size_t)(o0 + row) * CCH + c0 + cbl * 8, &At[nxt][(i * 32 + w * 8) * 64]);
        gld16(Bbase + (size_t)(n0 + row) * CCH + c0 + cbl * 8, &Bt[nxt][(i * 32 + w * 8) * 64]);
      }
    }
#pragma unroll
    for (int ks = 0; ks < 2; ++ks) {
      int phys = ((ks * 4 + quad) ^ (l16 & 7)) * 8;
      bf16x8 aW[2], bX[2];
#pragma unroll
      for (int ot = 0; ot < 2; ++ot)
        aW[ot] = *(const bf16x8*)&At[cur][(wy * 32 + ot * 16 + l16) * 64 + phys];
#pragma unroll
      for (int nt = 0; nt < 2; ++nt)
        bX[nt] = *(const bf16x8*)&Bt[cur][(wx * 32 + nt * 16 + l16) * 64 + phys];
#pragma unroll
      for (int ot = 0; ot < 2; ++ot)
#pragma unroll
        for (int nt = 0; nt < 2; ++nt)
          acc[ot][nt] =
              __builtin_amdgcn_mfma_f32_16x16x32_bf16(aW[ot], bX[nt], acc[ot][nt], 0, 0, 0);
    }
    __syncthreads();
  }

#pragma unroll
  for (int ot = 0; ot < 2; ++ot) {
#pragma unroll
    for (int r = 0; r < 4; ++r) {
      int o = o0 + wy * 32 + ot * 16 + quad * 4 + r;
      float br = bias[o];
#pragma unroll
      for (int nt = 0; nt < 2; ++nt)
        out[(size_t)b * ((size_t)CCH * NSEQ) + (size_t)o * NSEQ + n0 + wx * 32 + nt * 16 + l16] =
            acc[ot][nt][r] + br;
    }
  }
}

extern "C" void kernel_launch(void* const* d_in, const int* in_sizes, int n_in,
                              void* d_out, int out_size, void* d_ws, size_t ws_size,
                              hipStream_t stream) {
  const float* q = (const float*)d_in[0];
  const float* k = (const float*)d_in[1];
  const float* v = (const float*)d_in[2];
  const float* W = (const float*)d_in[3];
  const float* bias = (const float*)d_in[4];
  float* out = (float*)d_out;

  // ws layout (ushort units): Wp 1Mi | xt 4Mi | Kt 4Mi | Vb 4Mi = 26 MiB
  unsigned short* Wp = (unsigned short*)d_ws;
  unsigned short* xt = Wp + (1u << 20);
  unsigned short* Kt = xt + (4u << 20);
  unsigned short* Vb = Kt + (4u << 20);

  hipLaunchKernelGGL(prep_all, dim3(6144), dim3(256), 0, stream, W, v, k, Wp, Vb, Kt);
  hipLaunchKernelGGL(attn7, dim3(NSEQ / 64, H, BATCH), dim3(512), 0, stream, q, Kt, Vb, xt);
  hipLaunchKernelGGL(merge5, dim3(NSEQ / 64, CCH / 64, BATCH), dim3(256), 0, stream,
                     Wp, xt, bias, out);
}

// Round 8
// 161.877 us; speedup vs baseline: 4.2261x; 4.2261x over previous
//
#include <hip/hip_runtime.h>

// MHSA fused pipeline v8, MI355X gfx950.
// B=2, N=2048, C=1024, H=16, dim=64.
//
// v8 = v6 (best verified: attn 53us, total 160us) + three attributable fixes:
//  1) Q prep folded into attn prologue (raw fp32 Q read coalesced per block,
//     converted+swizzled into LDS) -> Qt buffer deleted (-16 MB traffic).
//  2) prep W section: LDS bounce transpose (was 16x over-fetch on 64B-strided
//     4B reads -> now coalesced float4 read + coalesced ushort4 write).
//  3) everything else (attn6 body, gld16 dbuf staging, merge5) verbatim.
// v7 lesson: per-lane strided register prefetch of V = 1 GB HBM overfetch; and
// 32 waves/CU is unreachable at ~104 unified regs/wave -> 16 waves/CU is the
// occupancy ceiling for this accumulator footprint.

#define H 16
#define NSEQ 2048
#define CCH 1024
#define BATCH 2
#define DSTR (H * NSEQ)  // 32768

typedef __attribute__((ext_vector_type(8))) short bf16x8;
typedef __attribute__((ext_vector_type(4))) float f32x4;
typedef __attribute__((ext_vector_type(16))) float f32x16;
typedef __attribute__((ext_vector_type(4))) unsigned int uint32x4;

__device__ __forceinline__ unsigned short f2bf(float x) {
  unsigned int u = __builtin_bit_cast(unsigned int, x);
  u += 0x7FFFu + ((u >> 16) & 1u);  // RNE
  return (unsigned short)(u >> 16);
}

__device__ __forceinline__ unsigned int pack2bf(float a, float b) {
#if __has_builtin(__builtin_amdgcn_cvt_pk_bf16_f32)
  typedef __attribute__((ext_vector_type(2))) __bf16 bf16x2_t;
  bf16x2_t r = __builtin_amdgcn_cvt_pk_bf16_f32(a, b);
  return __builtin_bit_cast(unsigned int, r);
#else
  unsigned int ua = __builtin_bit_cast(unsigned int, a);
  unsigned int ub = __builtin_bit_cast(unsigned int, b);
  ua += 0x7FFFu + ((ua >> 16) & 1u);
  ub += 0x7FFFu + ((ub >> 16) & 1u);
  return __builtin_amdgcn_perm(ub, ua, 0x07060302u);
#endif
}

__device__ __forceinline__ float fast_exp2(float x) {
#if __has_builtin(__builtin_amdgcn_exp2f)
  return __builtin_amdgcn_exp2f(x);
#else
  return exp2f(x);
#endif
}

__device__ __forceinline__ void permswap32(unsigned int& a, unsigned int& b) {
#if __has_builtin(__builtin_amdgcn_permlane32_swap)
  typedef __attribute__((ext_vector_type(2))) unsigned int uint2v;
  uint2v r = __builtin_amdgcn_permlane32_swap(a, b, false, false);
  a = r[0];
  b = r[1];
#else
  unsigned int ax = (unsigned int)__shfl_xor((int)a, 32, 64);
  unsigned int bx = (unsigned int)__shfl_xor((int)b, 32, 64);
  bool lo = (threadIdx.x & 63) < 32;
  unsigned int na = lo ? a : bx;
  unsigned int nb = lo ? ax : b;
  a = na;
  b = nb;
#endif
}

__device__ __forceinline__ void gld16(const void* g, void* l) {
  __builtin_amdgcn_global_load_lds(
      (const __attribute__((address_space(1))) unsigned int*)g,
      (__attribute__((address_space(3))) unsigned int*)l, 16, 0, 0);
}

__device__ __forceinline__ f32x16 zero16() {
  f32x16 v;
#pragma unroll
  for (int i = 0; i < 16; ++i) v[i] = 0.f;
  return v;
}

// ---------------- fused prep: W permute (LDS bounce) | V convert | K transpose ----
// grid: [0,1024) W-rows | [1024,5120) V float4 | [5120,6144) K 64-n tiles
__global__ __launch_bounds__(256) void prep_all(const float* __restrict__ W,
                                                const float* __restrict__ v,
                                                const float* __restrict__ k,
                                                unsigned short* __restrict__ Wp,
                                                unsigned short* __restrict__ Vb,
                                                unsigned short* __restrict__ Kt) {
  __shared__ unsigned short T[64][72];
  const int bid = blockIdx.x, tid = threadIdx.x;

  if (bid < 1024) {
    // one o-row per block: coalesced float4 read -> LDS -> coalesced ushort4
    // permuted write.  c = d*16+h  ->  c' = h*64+d.
    unsigned short* WT = &T[0][0];  // 1024 shorts used
    const int o = bid;
    float4 wv = ((const float4*)(W + (size_t)o * CCH))[tid];  // c = tid*4..+3
    WT[tid * 4 + 0] = f2bf(wv.x);
    WT[tid * 4 + 1] = f2bf(wv.y);
    WT[tid * 4 + 2] = f2bf(wv.z);
    WT[tid * 4 + 3] = f2bf(wv.w);
    __syncthreads();
    const int cp0 = tid * 4;
    ushort4 ov;
    ov.x = WT[((cp0 + 0) & 63) * 16 + ((cp0 + 0) >> 6)];
    ov.y = WT[((cp0 + 1) & 63) * 16 + ((cp0 + 1) >> 6)];
    ov.z = WT[((cp0 + 2) & 63) * 16 + ((cp0 + 2) >> 6)];
    ov.w = WT[((cp0 + 3) & 63) * 16 + ((cp0 + 3) >> 6)];
    *(ushort4*)&Wp[(size_t)o * CCH + cp0] = ov;
  } else if (bid < 5120) {
    int idx = (bid - 1024) * 256 + tid;
    float4 x = ((const float4*)v)[idx];
    ushort4 o;
    o.x = f2bf(x.x); o.y = f2bf(x.y); o.z = f2bf(x.z); o.w = f2bf(x.w);
    ((ushort4*)Vb)[idx] = o;
  } else {
    // K transpose+convert to [b][h][n][d]
    const int lbid = bid - 5120;
    const int n0 = (lbid & 31) * 64;
    const int hh = (lbid >> 5) & 15;
    const int b = lbid >> 9;
    const size_t base = (size_t)b * (CCH * NSEQ) + (size_t)hh * NSEQ;
#pragma unroll
    for (int it = 0; it < 4; ++it) {
      int i4 = it * 256 + tid;
      int d = i4 >> 4;
      int nn = (i4 & 15) << 2;
      float4 val = *(const float4*)(k + base + (size_t)d * DSTR + n0 + nn);
      T[nn + 0][d] = f2bf(val.x);
      T[nn + 1][d] = f2bf(val.y);
      T[nn + 2][d] = f2bf(val.z);
      T[nn + 3][d] = f2bf(val.w);
    }
    __syncthreads();
    const size_t obase = ((size_t)(b * H + hh) * NSEQ + n0) * 64;
#pragma unroll
    for (int it = 0; it < 2; ++it) {
      int idx = it * 256 + tid;
      int row = idx >> 3, cb = idx & 7;
      *(bf16x8*)(Kt + obase + (size_t)row * 64 + cb * 8) = *(const bf16x8*)&T[row][cb * 8];
    }
  }
}

// ---------------- attention v8 (= v6 + fp32-Q prologue fold) ----------------
// grid (16,16,2) = 512 blocks (2/CU), block 512 = 8 waves: g = m-group (2 x 1024 m),
// nw = n-wave (4 x 32 rows). 16 waves/CU resident.
__global__ __launch_bounds__(512, 4) void attn8(const float* __restrict__ q,
                                                const unsigned short* __restrict__ Kt,
                                                const unsigned short* __restrict__ Vb,
                                                unsigned short* __restrict__ xt) {
  // 64 KB K/V tiles ([g][buf][kv] x 8 KB) + 1 KB lsum; Q staged (16 KB) into the
  // KV area pre-loop; epilogue reuses KV area as Oex[128][64] f32 (32 KB).
  __shared__ __align__(16) unsigned char sbuf[65536 + 1024];
  unsigned short* KV = (unsigned short*)sbuf;
  float* lsumLDS = (float*)(sbuf + 65536);  // [2][128]
  float* Oex = (float*)sbuf;                // [128][64]
  unsigned short* Qs = KV;                  // [128][64] swizzled, transient

  const int tid = threadIdx.x;
  const int w = tid >> 6, lane = tid & 63;
  const int lane31 = lane & 31, hl = lane >> 5;
  const int g = w >> 2, nw = w & 3;
  const int n0 = blockIdx.x * 128;
  const int hh = blockIdx.y, b = blockIdx.z;

  const float* Qraw = q + (size_t)b * (CCH * NSEQ) + (size_t)hh * NSEQ;
  const unsigned short* Kg = Kt + ((size_t)(b * H + hh) * NSEQ + g * 1024) * 64;
  const unsigned short* Vg = Vb + (size_t)b * (CCH * NSEQ) + (size_t)hh * NSEQ + g * 1024;

  const int r8 = lane >> 3, scb = lane & 7;

#define KVOFF(gg, bb, kk) ((((gg)*2 + (bb)) * 2 + (kk)) * 4096)

  // ---- prologue: stage Q fp32 -> bf16, transposed+swizzled (scale folded) ----
  const float qscl = 0.022097086912079608f * 1.4426950408889634f;  // 1/sqrt(2048)*log2e
#pragma unroll
  for (int it2 = 0; it2 < 4; ++it2) {
    int i4 = it2 * 512 + tid;  // 2048 float4 = 64 d-rows x 128 n
    int d = i4 >> 5;
    int nn = (i4 & 31) << 2;
    float4 val = *(const float4*)(Qraw + (size_t)d * DSTR + n0 + nn);
    int ch = d >> 3, di = d & 7;
#pragma unroll
    for (int j = 0; j < 4; ++j) {
      float x = (j == 0) ? val.x : (j == 1) ? val.y : (j == 2) ? val.z : val.w;
      int n = nn + j;
      Qs[n * 64 + ((ch ^ (n & 7)) * 8 + di)] = f2bf(x * qscl);
    }
  }
  __syncthreads();

  // ---- loop-invariant Q B-fragments: B[col=n=lane31][k=d] ----
  bf16x8 bQ[4];
#pragma unroll
  for (int ks = 0; ks < 4; ++ks) {
    int row = nw * 32 + lane31;
    int phys = (ks * 2 + hl) ^ (row & 7);
    bQ[ks] = *(const bf16x8*)(KV + (size_t)row * 64 + phys * 8);
  }
  __syncthreads();  // Q reads done; KV becomes K/V tile space

  // ---- stage K/V iter 0 into buf 0 (each group its own m-range) ----
#pragma unroll
  for (int i = 0; i < 2; ++i) {
    int row = i * 32 + nw * 8 + r8;
    int cbl = scb ^ (row & 7);
    gld16(Kg + (size_t)row * 64 + cbl * 8, KV + KVOFF(g, 0, 0) + (i * 32 + nw * 8) * 64);
    gld16(Vg + (size_t)row * DSTR + cbl * 8, KV + KVOFF(g, 0, 1) + (i * 32 + nw * 8) * 64);
  }
  __syncthreads();

  f32x16 O[2];  // [dt]; col = d = dt*32+lane31, regs = n-rows
  O[0] = zero16();
  O[1] = zero16();
  float lsum = 0.f;

  for (int it = 0; it < 16; ++it) {
    const int cur = it & 1;
    if (it < 15) {
      const int nxt = cur ^ 1;
      const int m0n = (it + 1) * 64;
#pragma unroll
      for (int i = 0; i < 2; ++i) {
        int row = i * 32 + nw * 8 + r8;
        int cbl = scb ^ (row & 7);
        gld16(Kg + (size_t)(m0n + row) * 64 + cbl * 8,
              KV + KVOFF(g, nxt, 0) + (i * 32 + nw * 8) * 64);
        gld16(Vg + (size_t)row * DSTR + m0n + cbl * 8,
              KV + KVOFF(g, nxt, 1) + (i * 32 + nw * 8) * 64);
      }
    }

#pragma unroll
    for (int mt = 0; mt < 2; ++mt) {
      // St[m 32][n 32] = K . Q^T
      f32x16 St = zero16();
#pragma unroll
      for (int ks = 0; ks < 4; ++ks) {
        int row = mt * 32 + lane31;
        int phys = (ks * 2 + hl) ^ (row & 7);
        bf16x8 aK = *(const bf16x8*)(KV + KVOFF(g, cur, 0) + row * 64 + phys * 8);
        St = __builtin_amdgcn_mfma_f32_32x32x16_bf16(aK, bQ[ks], St, 0, 0, 0);
      }

      // P = exp2(St) (scale*log2e folded into Q), pack consecutive-m pairs
      unsigned int pd[8];
#pragma unroll
      for (int t = 0; t < 8; ++t) {
        float e0 = fast_exp2(St[2 * t]);
        float e1 = fast_exp2(St[2 * t + 1]);
        lsum += e0 + e1;
        pd[t] = pack2bf(e0, e1);
      }

      // C-layout -> A-layout in-register
      unsigned int s0[4] = {pd[0], pd[1], pd[2], pd[3]};
      unsigned int s1[4] = {pd[4], pd[5], pd[6], pd[7]};
      permswap32(s0[0], s0[2]);
      permswap32(s0[1], s0[3]);
      permswap32(s1[0], s1[2]);
      permswap32(s1[1], s1[3]);

      // PV: O[n][d] += P[n][m] . V[d][m]
#pragma unroll
      for (int ms = 0; ms < 2; ++ms) {
        bf16x8 bV[2];
#pragma unroll
        for (int dt = 0; dt < 2; ++dt) {
          int row = dt * 32 + lane31;
          int phys = (mt * 4 + ms * 2 + hl) ^ (row & 7);
          bV[dt] = *(const bf16x8*)(KV + KVOFF(g, cur, 1) + row * 64 + phys * 8);
        }
        const unsigned int* sp = ms ? s1 : s0;
        bf16x8 aP = __builtin_bit_cast(bf16x8, (uint32x4){sp[0], sp[1], sp[2], sp[3]});
        O[0] = __builtin_amdgcn_mfma_f32_32x32x16_bf16(aP, bV[0], O[0], 0, 0, 0);
        O[1] = __builtin_amdgcn_mfma_f32_32x32x16_bf16(aP, bV[1], O[1], 0, 0, 0);
      }
    }
    __syncthreads();
  }

  // ---- epilogue: combine the two m-groups in LDS, normalize, store ----
  lsum += __shfl_xor(lsum, 32, 64);
  if (hl == 0) lsumLDS[g * 128 + nw * 32 + lane31] = lsum;
  if (g == 1) {
#pragma unroll
    for (int dt = 0; dt < 2; ++dt)
#pragma unroll
      for (int r = 0; r < 16; ++r) {
        int nl = nw * 32 + (r & 3) + 8 * (r >> 2) + 4 * hl;
        Oex[nl * 64 + dt * 32 + lane31] = O[dt][r];
      }
  }
  __syncthreads();
  if (g == 0) {
    const size_t xb = (size_t)b * ((size_t)NSEQ * CCH);
#pragma unroll
    for (int rq = 0; rq < 4; ++rq) {
      int nlb = nw * 32 + rq * 8 + 4 * hl;
      float4 l0 = *(const float4*)&lsumLDS[nlb];
      float4 l1 = *(const float4*)&lsumLDS[128 + nlb];
      float inv0 = 1.0f / (l0.x + l1.x);
      float inv1 = 1.0f / (l0.y + l1.y);
      float inv2 = 1.0f / (l0.z + l1.z);
      float inv3 = 1.0f / (l0.w + l1.w);
#pragma unroll
      for (int dt = 0; dt < 2; ++dt) {
        int d = dt * 32 + lane31;
#pragma unroll
        for (int rr = 0; rr < 4; ++rr) {
          int r = rq * 4 + rr;
          float val = O[dt][r] + Oex[(nlb + rr) * 64 + d];
          float inv = (rr == 0) ? inv0 : (rr == 1) ? inv1 : (rr == 2) ? inv2 : inv3;
          int n = n0 + nlb + rr;
          xt[xb + (size_t)n * CCH + hh * 64 + d] = f2bf(val * inv);
        }
      }
    }
  }
#undef KVOFF
}

// ---------------- merge GEMM: 64x64 tiles, grid 1024 (4 blocks/CU), dbuf ----------------
__global__ __launch_bounds__(256) void merge5(const unsigned short* __restrict__ Wp,
                                              const unsigned short* __restrict__ xt,
                                              const float* __restrict__ bias,
                                              float* __restrict__ out) {
  __shared__ unsigned short At[2][64 * 64];
  __shared__ unsigned short Bt[2][64 * 64];
  const int tid = threadIdx.x;
  const int w = tid >> 6, lane = tid & 63;
  const int quad = lane >> 4, l16 = lane & 15;
  const int wx = w & 1, wy = w >> 1;
  const int n0 = blockIdx.x * 64, o0 = blockIdx.y * 64, b = blockIdx.z;
  const int srow = w * 8 + (lane >> 3), scb = lane & 7;
  const unsigned short* Bbase = xt + (size_t)b * ((size_t)NSEQ * CCH);

  f32x4 acc[2][2];
#pragma unroll
  for (int ot = 0; ot < 2; ++ot)
#pragma unroll
    for (int nt = 0; nt < 2; ++nt) acc[ot][nt] = (f32x4){0.f, 0.f, 0.f, 0.f};

#pragma unroll
  for (int i = 0; i < 2; ++i) {
    int row = i * 32 + srow;
    int cbl = scb ^ (row & 7);
    gld16(Wp + (size_t)(o0 + row) * CCH + cbl * 8, &At[0][(i * 32 + w * 8) * 64]);
    gld16(Bbase + (size_t)(n0 + row) * CCH + cbl * 8, &Bt[0][(i * 32 + w * 8) * 64]);
  }
  __syncthreads();

  for (int it = 0; it < 16; ++it) {
    const int cur = it & 1;
    if (it < 15) {
      const int nxt = cur ^ 1;
      const int c0 = (it + 1) * 64;
#pragma unroll
      for (int i = 0; i < 2; ++i) {
        int row = i * 32 + srow;
        int cbl = scb ^ (row & 7);
        gld16(Wp + (size_t)(o0 + row) * CCH + c0 + cbl * 8, &At[nxt][(i * 32 + w * 8) * 64]);
        gld16(Bbase + (size_t)(n0 + row) * CCH + c0 + cbl * 8, &Bt[nxt][(i * 32 + w * 8) * 64]);
      }
    }
#pragma unroll
    for (int ks = 0; ks < 2; ++ks) {
      int phys = ((ks * 4 + quad) ^ (l16 & 7)) * 8;
      bf16x8 aW[2], bX[2];
#pragma unroll
      for (int ot = 0; ot < 2; ++ot)
        aW[ot] = *(const bf16x8*)&At[cur][(wy * 32 + ot * 16 + l16) * 64 + phys];
#pragma unroll
      for (int nt = 0; nt < 2; ++nt)
        bX[nt] = *(const bf16x8*)&Bt[cur][(wx * 32 + nt * 16 + l16) * 64 + phys];
#pragma unroll
      for (int ot = 0; ot < 2; ++ot)
#pragma unroll
        for (int nt = 0; nt < 2; ++nt)
          acc[ot][nt] =
              __builtin_amdgcn_mfma_f32_16x16x32_bf16(aW[ot], bX[nt], acc[ot][nt], 0, 0, 0);
    }
    __syncthreads();
  }

#pragma unroll
  for (int ot = 0; ot < 2; ++ot) {
#pragma unroll
    for (int r = 0; r < 4; ++r) {
      int o = o0 + wy * 32 + ot * 16 + quad * 4 + r;
      float br = bias[o];
#pragma unroll
      for (int nt = 0; nt < 2; ++nt)
        out[(size_t)b * ((size_t)CCH * NSEQ) + (size_t)o * NSEQ + n0 + wx * 32 + nt * 16 + l16] =
            acc[ot][nt][r] + br;
    }
  }
}

extern "C" void kernel_launch(void* const* d_in, const int* in_sizes, int n_in,
                              void* d_out, int out_size, void* d_ws, size_t ws_size,
                              hipStream_t stream) {
  const float* q = (const float*)d_in[0];
  const float* k = (const float*)d_in[1];
  const float* v = (const float*)d_in[2];
  const float* W = (const float*)d_in[3];
  const float* bias = (const float*)d_in[4];
  float* out = (float*)d_out;

  // ws layout (ushort units): Wp 1Mi | xt 4Mi | Kt 4Mi | Vb 4Mi = 26 MiB
  unsigned short* Wp = (unsigned short*)d_ws;
  unsigned short* xt = Wp + (1u << 20);
  unsigned short* Kt = xt + (4u << 20);
  unsigned short* Vb = Kt + (4u << 20);

  hipLaunchKernelGGL(prep_all, dim3(6144), dim3(256), 0, stream, W, v, k, Wp, Vb, Kt);
  hipLaunchKernelGGL(attn8, dim3(NSEQ / 128, H, BATCH), dim3(512), 0, stream, q, Kt, Vb, xt);
  hipLaunchKernelGGL(merge5, dim3(NSEQ / 64, CCH / 64, BATCH), dim3(256), 0, stream,
                     Wp, xt, bias, out);
}